// Round 6
// baseline (171.540 us; speedup 1.0000x reference)
//
#include <hip/hip_runtime.h>
#include <math.h>

#define D_MODEL   1024
#define NUM_HEADS 16
#define HEAD_DIM  64
#define S_LEN     2048
#define BATCH     2
#define M_TOT     (BATCH * S_LEN)   // 4096

typedef __attribute__((ext_vector_type(8))) short short8;
typedef __attribute__((ext_vector_type(4))) short short4v;
typedef __attribute__((ext_vector_type(4))) float f32x4;

static __device__ __forceinline__ short f2bf(float f) {
    unsigned u = __builtin_bit_cast(unsigned, f);
    unsigned r = (u + 0x7FFFu + ((u >> 16) & 1u)) >> 16;   // RNE
    return (short)r;
}

typedef __attribute__((address_space(3))) void lds_v;
typedef const __attribute__((address_space(1))) void glb_v;
static __device__ __forceinline__ void gll16(const void* g, void* l) {
    // async global->LDS, 16B/lane, dest = wave-uniform base + lane*16
    __builtin_amdgcn_global_load_lds((glb_v*)g, (lds_v*)l, 16, 0, 0);
}

// ===========================================================================
// FAST PATH kernels
// ===========================================================================

// --- fused converts: blocks [0,2048) convert x; [2048,2304) transpose W -----
__global__ __launch_bounds__(256) void cvt_xw_kernel(
    const float* __restrict__ x, short* __restrict__ xb,
    const float* __restrict__ W, short* __restrict__ wt)
{
    __shared__ short T[64][72];
    const int bx = blockIdx.x;
    if (bx < 2048) {
        int i = (bx * 256 + threadIdx.x) * 8;
        float4 a = *(const float4*)(x + i);
        float4 b = *(const float4*)(x + i + 4);
        short8 o;
        o[0] = f2bf(a.x); o[1] = f2bf(a.y); o[2] = f2bf(a.z); o[3] = f2bf(a.w);
        o[4] = f2bf(b.x); o[5] = f2bf(b.y); o[6] = f2bf(b.z); o[7] = f2bf(b.w);
        *(short8*)(xb + i) = o;
    } else {
        const int t = bx - 2048;
        const int tid = threadIdx.x;
        const int k0 = (t >> 4) * 64, n0 = (t & 15) * 64;
        const int r = tid >> 4, c4 = (tid & 15) * 4;
        #pragma unroll
        for (int i = 0; i < 4; i++) {
            int kr = r + 16 * i;
            float4 v = *(const float4*)(W + (size_t)(k0 + kr) * D_MODEL + n0 + c4);
            short4v s;
            s[0] = f2bf(v.x); s[1] = f2bf(v.y); s[2] = f2bf(v.z); s[3] = f2bf(v.w);
            *(short4v*)&T[kr][c4] = s;
        }
        __syncthreads();
        const int n = tid >> 2, kb = (tid & 3) * 16;
        short tmp[16];
        #pragma unroll
        for (int j = 0; j < 16; j++) tmp[j] = T[kb + j][n];
        *(short8*)(wt + (size_t)(n0 + n) * D_MODEL + k0 + kb)     = *(short8*)&tmp[0];
        *(short8*)(wt + (size_t)(n0 + n) * D_MODEL + k0 + kb + 8) = *(short8*)&tmp[8];
    }
}

// --- bf16 MFMA GEMM + fused QKV epilogue (64x128 tile, 2 blocks/CU) ---------
__global__ __launch_bounds__(256) void gemm_qkv_kernel(
    const short* __restrict__ xb, const short* __restrict__ wt,
    const float* __restrict__ bias, const float* __restrict__ dq,
    const float* __restrict__ dk, const float* __restrict__ dv,
    short* __restrict__ Q, short* __restrict__ K, short* __restrict__ Vt)
{
    __shared__ __attribute__((aligned(16))) short lds[12288];

    const int tid  = threadIdx.x;
    const int w    = tid >> 6, l = tid & 63;
    const int quad = l >> 4,  c = l & 15;
    const int cx   = c & 7;
    const int n0 = blockIdx.x * 128, m0 = blockIdx.y * 64;
    const int wm = (w & 1) * 32, wn = (w >> 1) * 64;
    short* As = lds;          // [64][64]  swizzled
    short* Bs = lds + 4096;   // [128][64] swizzled

    const int srow  = l >> 3;
    const int sslot = (l & 7) ^ srow;

    f32x4 acc[2][4];
    #pragma unroll
    for (int mi = 0; mi < 2; mi++)
        #pragma unroll
        for (int ni = 0; ni < 4; ni++) acc[mi][ni] = (f32x4){0.f, 0.f, 0.f, 0.f};

    for (int k0 = 0; k0 < D_MODEL; k0 += 64) {
        __syncthreads();
        #pragma unroll
        for (int i = 0; i < 2; i++) {
            int rbase = 16 * w + 8 * i;
            gll16(xb + (size_t)(m0 + rbase + srow) * D_MODEL + k0 + sslot * 8,
                  As + rbase * 64);
        }
        #pragma unroll
        for (int i = 0; i < 4; i++) {
            int rbase = 32 * w + 8 * i;
            gll16(wt + (size_t)(n0 + rbase + srow) * D_MODEL + k0 + sslot * 8,
                  Bs + rbase * 64);
        }
        __syncthreads();
        #pragma unroll
        for (int kh = 0; kh < 2; kh++) {
            const int sx = (kh * 4 + quad) ^ cx;
            short8 af[2], bf[4];
            #pragma unroll
            for (int mi = 0; mi < 2; mi++)
                af[mi] = *(const short8*)&As[(wm + 16 * mi + c) * 64 + sx * 8];
            #pragma unroll
            for (int ni = 0; ni < 4; ni++)
                bf[ni] = *(const short8*)&Bs[(wn + 16 * ni + c) * 64 + sx * 8];
            #pragma unroll
            for (int mi = 0; mi < 2; mi++)
                #pragma unroll
                for (int ni = 0; ni < 4; ni++)
                    acc[mi][ni] = __builtin_amdgcn_mfma_f32_16x16x32_bf16(
                        af[mi], bf[ni], acc[mi][ni], 0, 0, 0);
        }
    }

    __syncthreads();
    const int b      = m0 >> 11;
    const int s_base = m0 & 2047;
    const int h      = (n0 + wn) >> 6;

    float biasv[4], dqv[4], dkv[4], dvv[4];
    #pragma unroll
    for (int ni = 0; ni < 4; ni++) {
        int n_g = n0 + wn + 16 * ni + c;
        biasv[ni] = bias[n_g]; dqv[ni] = dq[n_g];
        dkv[ni] = dk[n_g];     dvv[ni] = dv[n_g];
    }

    short* E = lds;   // [128 n][72 m]
    #pragma unroll
    for (int mi = 0; mi < 2; mi++) {
        #pragma unroll
        for (int ni = 0; ni < 4; ni++) {
            short4v vv;
            #pragma unroll
            for (int r = 0; r < 4; r++) {
                float xv = acc[mi][ni][r] + biasv[ni];
                int s = s_base + wm + 16 * mi + 4 * quad + r;
                size_t off = (((size_t)(b * NUM_HEADS + h) * S_LEN + s) << 6) + (16 * ni + c);
                Q[off] = f2bf(xv * dqv[ni]);
                K[off] = f2bf(xv * dkv[ni]);
                vv[r]  = f2bf(xv * dvv[ni]);
            }
            int n_l = wn + 16 * ni + c;
            int m_l = wm + 16 * mi + 4 * quad;
            *(short4v*)&E[n_l * 72 + m_l] = vv;
        }
    }
    __syncthreads();
    {
        const int n_l = tid >> 1, mh = (tid & 1) * 32;
        const int h2 = (n0 + n_l) >> 6;
        const int dh = n_l & 63;
        short* dst = Vt + ((size_t)(b * NUM_HEADS + h2) * HEAD_DIM + dh) * S_LEN + s_base;
        #pragma unroll
        for (int ch = 0; ch < 4; ch++) {
            short8 v = *(const short8*)&E[n_l * 72 + mh + ch * 8];
            *(short8*)(dst + mh + ch * 8) = v;
        }
    }
}

// --- split-K attention: each block does 1024 keys for 128 q-rows ------------
// Writes unnormalized O-partials (fp32) + denom partials; combine divides.
// Denominator computed via extra MFMA (P . ones) -> lands in same C-layout
// rows (4*quad+r) as the O accumulator; no shuffles needed.
__global__ __launch_bounds__(256) void attn_split_kernel(
    const short* __restrict__ Q, const short* __restrict__ K,
    const short* __restrict__ Vt, float* __restrict__ Opart,
    float* __restrict__ dpart)
{
    __shared__ __attribute__((aligned(16))) short lds[8192 + 4 * 32 * 88];

    const int tid  = threadIdx.x;
    const int w    = tid >> 6, l = tid & 63;
    const int quad = l >> 4,  c = l & 15;
    const int cx   = c & 7;
    const int qt    = blockIdx.x >> 1;
    const int split = blockIdx.x & 1;
    const int q0 = qt * 128;
    const int h  = blockIdx.y, b = blockIdx.z;
    const size_t bh = (size_t)(b * NUM_HEADS + h);
    const short* Qh  = Q  + bh * S_LEN * HEAD_DIM;
    const short* Kh  = K  + bh * S_LEN * HEAD_DIM;
    const short* Vth = Vt + bh * HEAD_DIM * S_LEN;

    short* Ks = lds;                         // [64][64] swizzled
    short* Vs = lds + 4096;                  // [64][64] d-major, swizzled
    short* Ps = lds + 8192 + w * (32 * 88);  // per-wave [32][88]

    const int srow  = l >> 3;
    const int sslot = (l & 7) ^ srow;

    short8 qf0[2], qf1[2];
    {
        const short* qp0 = Qh + (size_t)(q0 + 32 * w + c) * 64 + quad * 8;
        const short* qp1 = qp0 + 16 * 64;
        qf0[0] = *(const short8*)(qp0);
        qf0[1] = *(const short8*)(qp0 + 32);
        qf1[0] = *(const short8*)(qp1);
        qf1[1] = *(const short8*)(qp1 + 32);
    }

    short8 ones;
    #pragma unroll
    for (int j = 0; j < 8; j++) ones[j] = (short)0x3F80;  // bf16 1.0

    f32x4 o0[4], o1[4], d0a, d1a;
    #pragma unroll
    for (int i = 0; i < 4; i++) {
        o0[i] = (f32x4){0.f, 0.f, 0.f, 0.f};
        o1[i] = (f32x4){0.f, 0.f, 0.f, 0.f};
    }
    d0a = (f32x4){0.f, 0.f, 0.f, 0.f};
    d1a = (f32x4){0.f, 0.f, 0.f, 0.f};

    const int kt_beg = split * (S_LEN / 128);
    for (int kt = kt_beg; kt < kt_beg + S_LEN / 128; kt++) {
        const int k0 = kt * 64;
        __syncthreads();
        #pragma unroll
        for (int i = 0; i < 2; i++) {
            int rbase = 16 * w + 8 * i;
            int row = rbase + srow;
            gll16(Kh + (size_t)(k0 + row) * 64 + sslot * 8, Ks + rbase * 64);
            gll16(Vth + (size_t)row * S_LEN + k0 + sslot * 8, Vs + rbase * 64);
        }
        __syncthreads();

        // S^T = K . Q^T for both halves; kf read once, used twice
        f32x4 s0[4], s1[4];
        #pragma unroll
        for (int n = 0; n < 4; n++) {
            s0[n] = (f32x4){0.f, 0.f, 0.f, 0.f};
            s1[n] = (f32x4){0.f, 0.f, 0.f, 0.f};
        }
        #pragma unroll
        for (int hh = 0; hh < 2; hh++) {
            const int sx = (hh * 4 + quad) ^ cx;
            #pragma unroll
            for (int n = 0; n < 4; n++) {
                short8 kf = *(const short8*)&Ks[(16 * n + c) * 64 + sx * 8];
                s0[n] = __builtin_amdgcn_mfma_f32_16x16x32_bf16(kf, qf0[hh], s0[n], 0, 0, 0);
                s1[n] = __builtin_amdgcn_mfma_f32_16x16x32_bf16(kf, qf1[hh], s1[n], 0, 0, 0);
            }
        }

        // numerator -> P (round-half-up bf16 pack via v_perm)
        #pragma unroll
        for (int n = 0; n < 4; n++) {
            float nm[4];
            #pragma unroll
            for (int r = 0; r < 4; r++) {
                float z = __builtin_amdgcn_fmed3f(s0[n][r], -15.0f, 15.0f);
                float e = __builtin_amdgcn_exp2f(
                    __builtin_fmaf(z, 1.4426950408889634f, -1.4426950408889634f));
                nm[r] = fmaxf(__builtin_fmaf(z, 0.1f, e), 0.0f);
            }
            unsigned p0 = __builtin_amdgcn_perm(
                __builtin_bit_cast(unsigned, nm[1]) + 0x8000u,
                __builtin_bit_cast(unsigned, nm[0]) + 0x8000u, 0x07060302u);
            unsigned p1 = __builtin_amdgcn_perm(
                __builtin_bit_cast(unsigned, nm[3]) + 0x8000u,
                __builtin_bit_cast(unsigned, nm[2]) + 0x8000u, 0x07060302u);
            uint2 pr; pr.x = p0; pr.y = p1;
            *(uint2*)&Ps[c * 88 + 16 * n + 4 * quad] = pr;
        }
        #pragma unroll
        for (int n = 0; n < 4; n++) {
            float nm[4];
            #pragma unroll
            for (int r = 0; r < 4; r++) {
                float z = __builtin_amdgcn_fmed3f(s1[n][r], -15.0f, 15.0f);
                float e = __builtin_amdgcn_exp2f(
                    __builtin_fmaf(z, 1.4426950408889634f, -1.4426950408889634f));
                nm[r] = fmaxf(__builtin_fmaf(z, 0.1f, e), 0.0f);
            }
            unsigned p0 = __builtin_amdgcn_perm(
                __builtin_bit_cast(unsigned, nm[1]) + 0x8000u,
                __builtin_bit_cast(unsigned, nm[0]) + 0x8000u, 0x07060302u);
            unsigned p1 = __builtin_amdgcn_perm(
                __builtin_bit_cast(unsigned, nm[3]) + 0x8000u,
                __builtin_bit_cast(unsigned, nm[2]) + 0x8000u, 0x07060302u);
            uint2 pr; pr.x = p0; pr.y = p1;
            *(uint2*)&Ps[(16 + c) * 88 + 16 * n + 4 * quad] = pr;
        }
        // no barrier: Ps is same-wave produce/consume (lgkmcnt orders it)

        // PV + denominator row-sum; vf read once, used twice
        #pragma unroll
        for (int kh = 0; kh < 2; kh++) {
            short8 pf0 = *(const short8*)&Ps[c * 88 + 32 * kh + 8 * quad];
            short8 pf1 = *(const short8*)&Ps[(16 + c) * 88 + 32 * kh + 8 * quad];
            const int sx = (kh * 4 + quad) ^ cx;
            #pragma unroll
            for (int n2 = 0; n2 < 4; n2++) {
                short8 vf = *(const short8*)&Vs[(16 * n2 + c) * 64 + sx * 8];
                o0[n2] = __builtin_amdgcn_mfma_f32_16x16x32_bf16(pf0, vf, o0[n2], 0, 0, 0);
                o1[n2] = __builtin_amdgcn_mfma_f32_16x16x32_bf16(pf1, vf, o1[n2], 0, 0, 0);
            }
            d0a = __builtin_amdgcn_mfma_f32_16x16x32_bf16(pf0, ones, d0a, 0, 0, 0);
            d1a = __builtin_amdgcn_mfma_f32_16x16x32_bf16(pf1, ones, d1a, 0, 0, 0);
        }
    }

    // --- write partials: Opart[split][b][h][qt][128][64], dpart[...][128] ---
    float* Op = Opart + ((((size_t)split * BATCH + b) * NUM_HEADS + h) * 16 + qt) * (128 * 64);
    float* dp = dpart + ((((size_t)split * BATCH + b) * NUM_HEADS + h) * 16 + qt) * 128;

    #pragma unroll
    for (int r = 0; r < 4; r++) {
        int row0 = 32 * w + 4 * quad + r;
        #pragma unroll
        for (int n2 = 0; n2 < 4; n2++) {
            Op[row0 * 64 + 16 * n2 + c]        = o0[n2][r];
            Op[(row0 + 16) * 64 + 16 * n2 + c] = o1[n2][r];
        }
        if (c == 0) {
            dp[row0]      = d0a[r];
            dp[row0 + 16] = d1a[r];
        }
    }
}

// --- combine: out = (O0 + O1) / (d0 + d1 + eps) -----------------------------
__global__ __launch_bounds__(256) void combine_kernel(
    const float* __restrict__ Opart, const float* __restrict__ dpart,
    float* __restrict__ out)
{
    const int gid = blockIdx.x * 256 + threadIdx.x;   // [0, 1048576)
    const int row = gid >> 4;                          // [0, 65536)
    const int col = (gid & 15) * 4;
    float d = dpart[row] + dpart[65536 + row] + 1e-9f;
    float inv = 1.0f / d;
    float4 a = *(const float4*)(Opart + (size_t)gid * 4);
    float4 bb = *(const float4*)(Opart + 4194304 + (size_t)gid * 4);
    const int b = row >> 15;
    const int h = (row >> 11) & 15;
    const int s = row & 2047;
    float4 r;
    r.x = (a.x + bb.x) * inv; r.y = (a.y + bb.y) * inv;
    r.z = (a.z + bb.z) * inv; r.w = (a.w + bb.w) * inv;
    *(float4*)(out + ((size_t)(b * S_LEN + s) << 10) + (h << 6) + col) = r;
}

// --- middle tier: round-5 attention (full keys, divides in-kernel) ----------
__global__ __launch_bounds__(256) void attn2_kernel(
    const short* __restrict__ Q, const short* __restrict__ K,
    const short* __restrict__ Vt, float* __restrict__ out)
{
    __shared__ __attribute__((aligned(16))) short lds[8192 + 4 * 32 * 88];

    const int tid  = threadIdx.x;
    const int w    = tid >> 6, l = tid & 63;
    const int quad = l >> 4,  c = l & 15;
    const int cx   = c & 7;
    const int q0 = blockIdx.x * 128;
    const int h  = blockIdx.y, b = blockIdx.z;
    const size_t bh = (size_t)(b * NUM_HEADS + h);
    const short* Qh  = Q  + bh * S_LEN * HEAD_DIM;
    const short* Kh  = K  + bh * S_LEN * HEAD_DIM;
    const short* Vth = Vt + bh * HEAD_DIM * S_LEN;

    short* Ks = lds;
    short* Vs = lds + 4096;
    short* Ps = lds + 8192 + w * (32 * 88);

    const int srow  = l >> 3;
    const int sslot = (l & 7) ^ srow;

    short8 qf0[2], qf1[2];
    {
        const short* qp0 = Qh + (size_t)(q0 + 32 * w + c) * 64 + quad * 8;
        const short* qp1 = qp0 + 16 * 64;
        qf0[0] = *(const short8*)(qp0);
        qf0[1] = *(const short8*)(qp0 + 32);
        qf1[0] = *(const short8*)(qp1);
        qf1[1] = *(const short8*)(qp1 + 32);
    }

    f32x4 o0[4], o1[4];
    #pragma unroll
    for (int i = 0; i < 4; i++) {
        o0[i] = (f32x4){0.f, 0.f, 0.f, 0.f};
        o1[i] = (f32x4){0.f, 0.f, 0.f, 0.f};
    }
    float dnm0 = 0.0f, dnm1 = 0.0f;

    for (int kt = 0; kt < S_LEN / 64; kt++) {
        const int k0 = kt * 64;
        __syncthreads();
        #pragma unroll
        for (int i = 0; i < 2; i++) {
            int rbase = 16 * w + 8 * i;
            int row = rbase + srow;
            gll16(Kh + (size_t)(k0 + row) * 64 + sslot * 8, Ks + rbase * 64);
            gll16(Vth + (size_t)row * S_LEN + k0 + sslot * 8, Vs + rbase * 64);
        }
        __syncthreads();

        f32x4 s0[4], s1[4];
        #pragma unroll
        for (int n = 0; n < 4; n++) {
            s0[n] = (f32x4){0.f, 0.f, 0.f, 0.f};
            s1[n] = (f32x4){0.f, 0.f, 0.f, 0.f};
        }
        #pragma unroll
        for (int hh = 0; hh < 2; hh++) {
            const int sx = (hh * 4 + quad) ^ cx;
            #pragma unroll
            for (int n = 0; n < 4; n++) {
                short8 kf = *(const short8*)&Ks[(16 * n + c) * 64 + sx * 8];
                s0[n] = __builtin_amdgcn_mfma_f32_16x16x32_bf16(kf, qf0[hh], s0[n], 0, 0, 0);
                s1[n] = __builtin_amdgcn_mfma_f32_16x16x32_bf16(kf, qf1[hh], s1[n], 0, 0, 0);
            }
        }

        #pragma unroll
        for (int n = 0; n < 4; n++) {
            float nm[4];
            #pragma unroll
            for (int r = 0; r < 4; r++) {
                float z = __builtin_amdgcn_fmed3f(s0[n][r], -15.0f, 15.0f);
                float e = __builtin_amdgcn_exp2f(
                    __builtin_fmaf(z, 1.4426950408889634f, -1.4426950408889634f));
                float num = fmaxf(__builtin_fmaf(z, 0.1f, e), 0.0f);
                dnm0 += num;
                nm[r] = num;
            }
            unsigned p0 = __builtin_amdgcn_perm(
                __builtin_bit_cast(unsigned, nm[1]) + 0x8000u,
                __builtin_bit_cast(unsigned, nm[0]) + 0x8000u, 0x07060302u);
            unsigned p1 = __builtin_amdgcn_perm(
                __builtin_bit_cast(unsigned, nm[3]) + 0x8000u,
                __builtin_bit_cast(unsigned, nm[2]) + 0x8000u, 0x07060302u);
            uint2 pr; pr.x = p0; pr.y = p1;
            *(uint2*)&Ps[c * 88 + 16 * n + 4 * quad] = pr;
        }
        #pragma unroll
        for (int n = 0; n < 4; n++) {
            float nm[4];
            #pragma unroll
            for (int r = 0; r < 4; r++) {
                float z = __builtin_amdgcn_fmed3f(s1[n][r], -15.0f, 15.0f);
                float e = __builtin_amdgcn_exp2f(
                    __builtin_fmaf(z, 1.4426950408889634f, -1.4426950408889634f));
                float num = fmaxf(__builtin_fmaf(z, 0.1f, e), 0.0f);
                dnm1 += num;
                nm[r] = num;
            }
            unsigned p0 = __builtin_amdgcn_perm(
                __builtin_bit_cast(unsigned, nm[1]) + 0x8000u,
                __builtin_bit_cast(unsigned, nm[0]) + 0x8000u, 0x07060302u);
            unsigned p1 = __builtin_amdgcn_perm(
                __builtin_bit_cast(unsigned, nm[3]) + 0x8000u,
                __builtin_bit_cast(unsigned, nm[2]) + 0x8000u, 0x07060302u);
            uint2 pr; pr.x = p0; pr.y = p1;
            *(uint2*)&Ps[(16 + c) * 88 + 16 * n + 4 * quad] = pr;
        }

        #pragma unroll
        for (int kh = 0; kh < 2; kh++) {
            short8 pf0 = *(const short8*)&Ps[c * 88 + 32 * kh + 8 * quad];
            short8 pf1 = *(const short8*)&Ps[(16 + c) * 88 + 32 * kh + 8 * quad];
            const int sx = (kh * 4 + quad) ^ cx;
            #pragma unroll
            for (int n2 = 0; n2 < 4; n2++) {
                short8 vf = *(const short8*)&Vs[(16 * n2 + c) * 64 + sx * 8];
                o0[n2] = __builtin_amdgcn_mfma_f32_16x16x32_bf16(pf0, vf, o0[n2], 0, 0, 0);
                o1[n2] = __builtin_amdgcn_mfma_f32_16x16x32_bf16(pf1, vf, o1[n2], 0, 0, 0);
            }
        }
    }

    dnm0 += __shfl_xor(dnm0, 16, 64);
    dnm0 += __shfl_xor(dnm0, 32, 64);
    dnm1 += __shfl_xor(dnm1, 16, 64);
    dnm1 += __shfl_xor(dnm1, 32, 64);

    #pragma unroll
    for (int r = 0; r < 4; r++) {
        float dr0 = __shfl(dnm0, quad * 4 + r, 64);
        float dr1 = __shfl(dnm1, quad * 4 + r, 64);
        float inv0 = 1.0f / (dr0 + 1e-9f);
        float inv1 = 1.0f / (dr1 + 1e-9f);
        int qrow0 = q0 + 32 * w + 4 * quad + r;
        float* op0 = out + ((size_t)(b * S_LEN + qrow0) << 10) + (h << 6) + c;
        float* op1 = op0 + (16 << 10);
        #pragma unroll
        for (int n2 = 0; n2 < 4; n2++) {
            op0[16 * n2] = o0[n2][r] * inv0;
            op1[16 * n2] = o1[n2][r] * inv1;
        }
    }
}

// ===========================================================================
// FALLBACK PATH (fp32, needs 16 MB workspace)
// ===========================================================================
__global__ __launch_bounds__(256, 4) void gemm_xw_kernel(
    const float* __restrict__ x, const float* __restrict__ W,
    const float* __restrict__ bias, float* __restrict__ xp)
{
    __shared__ float Asf[64][36];
    __shared__ float Bsf[32][68];

    const int tid = threadIdx.x;
    const int tx  = tid & 15;
    const int ty  = tid >> 4;
    const int m0  = blockIdx.y * 64;
    const int n0  = blockIdx.x * 64;

    float acc[4][4];
    #pragma unroll
    for (int i = 0; i < 4; i++)
        #pragma unroll
        for (int j = 0; j < 4; j++) acc[i][j] = 0.0f;

    for (int k0 = 0; k0 < D_MODEL; k0 += 32) {
        #pragma unroll
        for (int i = 0; i < 2; i++) {
            int idx = tid + i * 256;
            int r = idx >> 3, c4 = idx & 7;
            *(float4*)(&Asf[r][c4 * 4]) =
                *(const float4*)(x + (size_t)(m0 + r) * D_MODEL + k0 + c4 * 4);
        }
        #pragma unroll
        for (int i = 0; i < 2; i++) {
            int idx = tid + i * 256;
            int r = idx >> 4, c4 = idx & 15;
            *(float4*)(&Bsf[r][c4 * 4]) =
                *(const float4*)(W + (size_t)(k0 + r) * D_MODEL + n0 + c4 * 4);
        }
        __syncthreads();
        #pragma unroll
        for (int k = 0; k < 32; k += 4) {
            float a[4][4];
            #pragma unroll
            for (int i = 0; i < 4; i++) {
                float4 t = *(const float4*)(&Asf[ty + 16 * i][k]);
                a[i][0] = t.x; a[i][1] = t.y; a[i][2] = t.z; a[i][3] = t.w;
            }
            #pragma unroll
            for (int kk = 0; kk < 4; kk++) {
                float4 bv = *(const float4*)(&Bsf[k + kk][tx * 4]);
                #pragma unroll
                for (int i = 0; i < 4; i++) {
                    acc[i][0] += a[i][kk] * bv.x;
                    acc[i][1] += a[i][kk] * bv.y;
                    acc[i][2] += a[i][kk] * bv.z;
                    acc[i][3] += a[i][kk] * bv.w;
                }
            }
        }
        __syncthreads();
    }
    float4 bv = *(const float4*)(bias + n0 + tx * 4);
    #pragma unroll
    for (int i = 0; i < 4; i++) {
        float4 r;
        r.x = acc[i][0] + bv.x; r.y = acc[i][1] + bv.y;
        r.z = acc[i][2] + bv.z; r.w = acc[i][3] + bv.w;
        *(float4*)(xp + (size_t)(m0 + ty + 16 * i) * D_MODEL + n0 + tx * 4) = r;
    }
}

__global__ __launch_bounds__(256, 4) void attn_fb_kernel(
    const float* __restrict__ xp, const float* __restrict__ dq,
    const float* __restrict__ dk, const float* __restrict__ dv,
    float* __restrict__ out)
{
    __shared__ __attribute__((aligned(16))) short lds[13824];

    const int tid  = threadIdx.x;
    const int wave = tid >> 6;
    const int l    = tid & 63;
    const int quad = l >> 4;
    const int c    = l & 15;
    const int q0   = blockIdx.x * 64;
    const int h    = blockIdx.y;
    const int bb   = blockIdx.z;
    const int col0 = h * HEAD_DIM;
    const float* base = xp + (size_t)bb * S_LEN * D_MODEL;

    short* Ks = lds;
    short* Vt = lds + 64 * 72;
    short* Ps = lds + 2 * 64 * 72 + wave * (16 * 72);

    short8 qf[2];
    {
        const int qrow = q0 + wave * 16 + c;
        const float* qp = base + (size_t)qrow * D_MODEL + col0 + quad * 8;
        const float* sp = dq + col0 + quad * 8;
        #pragma unroll
        for (int hh = 0; hh < 2; hh++) {
            float4 v0 = *(const float4*)(qp + 32 * hh);
            float4 v1 = *(const float4*)(qp + 32 * hh + 4);
            float4 s0 = *(const float4*)(sp + 32 * hh);
            float4 s1 = *(const float4*)(sp + 32 * hh + 4);
            qf[hh][0] = f2bf(v0.x * s0.x); qf[hh][1] = f2bf(v0.y * s0.y);
            qf[hh][2] = f2bf(v0.z * s0.z); qf[hh][3] = f2bf(v0.w * s0.w);
            qf[hh][4] = f2bf(v1.x * s1.x); qf[hh][5] = f2bf(v1.y * s1.y);
            qf[hh][6] = f2bf(v1.z * s1.z); qf[hh][7] = f2bf(v1.w * s1.w);
        }
    }

    const int sc4  = 4 * (tid & 15);
    const int srow = tid >> 4;
    const float4 ksc = *(const float4*)(dk + col0 + sc4);
    const int vd = tid & 63;
    const int vg = tid >> 6;
    const float vsc = dv[col0 + vd];

    f32x4 acc_o[4];
    #pragma unroll
    for (int i = 0; i < 4; i++) acc_o[i] = (f32x4){0.f, 0.f, 0.f, 0.f};
    float dnm = 0.0f;

    for (int kt = 0; kt < S_LEN / 64; kt++) {
        const int k0 = kt * 64;
        __syncthreads();

        #pragma unroll
        for (int i = 0; i < 4; i++) {
            int r = srow + 16 * i;
            float4 v = *(const float4*)(base + (size_t)(k0 + r) * D_MODEL + col0 + sc4);
            short4v s;
            s[0] = f2bf(v.x * ksc.x); s[1] = f2bf(v.y * ksc.y);
            s[2] = f2bf(v.z * ksc.z); s[3] = f2bf(v.w * ksc.w);
            *(short4v*)&Ks[r * 72 + sc4] = s;
        }
        #pragma unroll
        for (int p = 0; p < 4; p++) {
            int kb = 16 * p + 4 * vg;
            const float* vp = base + (size_t)(k0 + kb) * D_MODEL + col0 + vd;
            float a0 = vp[0 * D_MODEL], a1 = vp[1 * D_MODEL];
            float a2 = vp[2 * D_MODEL], a3 = vp[3 * D_MODEL];
            short4v s;
            s[0] = f2bf(a0 * vsc); s[1] = f2bf(a1 * vsc);
            s[2] = f2bf(a2 * vsc); s[3] = f2bf(a3 * vsc);
            *(short4v*)&Vt[vd * 72 + kb] = s;
        }
        __syncthreads();

        f32x4 sacc[4];
        #pragma unroll
        for (int n = 0; n < 4; n++) sacc[n] = (f32x4){0.f, 0.f, 0.f, 0.f};
        #pragma unroll
        for (int n = 0; n < 4; n++)
            #pragma unroll
            for (int hh = 0; hh < 2; hh++) {
                short8 kf = *(const short8*)&Ks[(16 * n + c) * 72 + 32 * hh + 8 * quad];
                sacc[n] = __builtin_amdgcn_mfma_f32_16x16x32_bf16(kf, qf[hh], sacc[n], 0, 0, 0);
            }

        #pragma unroll
        for (int n = 0; n < 4; n++) {
            short4v pp;
            #pragma unroll
            for (int r = 0; r < 4; r++) {
                float z = fminf(fmaxf(sacc[n][r], -15.0f), 15.0f);
                float e = __expf(z - 1.0f);
                float num = fmaxf(fmaf(z, 0.1f, e), 0.0f);
                dnm += num;
                pp[r] = f2bf(num);
            }
            *(short4v*)&Ps[c * 72 + 16 * n + 4 * quad] = pp;
        }

        #pragma unroll
        for (int kh = 0; kh < 2; kh++) {
            short8 pf = *(const short8*)&Ps[c * 72 + 32 * kh + 8 * quad];
            #pragma unroll
            for (int n2 = 0; n2 < 4; n2++) {
                short8 vf = *(const short8*)&Vt[(16 * n2 + c) * 72 + 32 * kh + 8 * quad];
                acc_o[n2] = __builtin_amdgcn_mfma_f32_16x16x32_bf16(pf, vf, acc_o[n2], 0, 0, 0);
            }
        }
    }

    dnm += __shfl_xor(dnm, 16, 64);
    dnm += __shfl_xor(dnm, 32, 64);

    #pragma unroll
    for (int r = 0; r < 4; r++) {
        float dr  = __shfl(dnm, quad * 4 + r, 64);
        float inv = 1.0f / (dr + 1e-9f);
        const int qrow = q0 + wave * 16 + quad * 4 + r;
        float* op = out + (size_t)(bb * S_LEN + qrow) * D_MODEL + col0 + c;
        #pragma unroll
        for (int n2 = 0; n2 < 4; n2++)
            op[16 * n2] = acc_o[n2][r] * inv;
    }
}

// ===========================================================================
extern "C" void kernel_launch(void* const* d_in, const int* in_sizes, int n_in,
                              void* d_out, int out_size, void* d_ws, size_t ws_size,
                              hipStream_t stream) {
    const float* x  = (const float*)d_in[0];
    const float* W  = (const float*)d_in[1];
    const float* bias = (const float*)d_in[2];
    const float* dq = (const float*)d_in[3];
    const float* dk = (const float*)d_in[4];
    const float* dv = (const float*)d_in[5];
    float* out = (float*)d_out;

    const size_t XB_B = (size_t)M_TOT * D_MODEL * 2;        // 8 MB
    const size_t WT_B = (size_t)D_MODEL * D_MODEL * 2;      // 2 MB
    const size_t T_B  = (size_t)BATCH * NUM_HEADS * S_LEN * HEAD_DIM * 2; // 8 MB each
    const size_t OP_B = (size_t)2 * 65536 * 64 * 4;         // 33.55 MB
    const size_t DP_B = (size_t)2 * 65536 * 4;              // 512 KB
    const size_t NEED1 = XB_B + WT_B + 3 * T_B;             // ~34 MB
    const size_t NEED2 = NEED1 + OP_B + DP_B;               // ~68.2 MB

    if (ws_size >= NEED1) {
        char* p = (char*)d_ws;
        short* xb = (short*)p;             p += XB_B;
        short* wt = (short*)p;             p += WT_B;
        short* Qt = (short*)p;             p += T_B;
        short* Kt = (short*)p;             p += T_B;
        short* Vt = (short*)p;             p += T_B;

        cvt_xw_kernel<<<2048 + 256, 256, 0, stream>>>(x, xb, W, wt);
        dim3 gg(D_MODEL / 128, M_TOT / 64);                // (8, 64) = 512 blocks
        gemm_qkv_kernel<<<gg, 256, 0, stream>>>(xb, wt, bias, dq, dk, dv, Qt, Kt, Vt);

        if (ws_size >= NEED2) {
            float* Opart = (float*)p;      p += OP_B;
            float* dpart = (float*)p;
            dim3 ga(2 * S_LEN / 128, NUM_HEADS, BATCH);    // (32, 16, 2) = 1024 blocks
            attn_split_kernel<<<ga, 256, 0, stream>>>(Qt, Kt, Vt, Opart, dpart);
            combine_kernel<<<4096, 256, 0, stream>>>(Opart, dpart, out);
        } else {
            dim3 ga(S_LEN / 128, NUM_HEADS, BATCH);        // (16, 16, 2) = 512 blocks
            attn2_kernel<<<ga, 256, 0, stream>>>(Qt, Kt, Vt, out);
        }
    } else {
        float* xp = (float*)d_ws;   // 16 MB
        dim3 g1(D_MODEL / 64, M_TOT / 64);
        gemm_xw_kernel<<<g1, 256, 0, stream>>>(x, W, bias, xp);
        dim3 g2(S_LEN / 64, NUM_HEADS, BATCH);
        attn_fb_kernel<<<g2, 256, 0, stream>>>(xp, dq, dk, dv, out);
    }
}

// Round 7
// 155.698 us; speedup vs baseline: 1.1017x; 1.1017x over previous
//
#include <hip/hip_runtime.h>
#include <math.h>

#define D_MODEL   1024
#define NUM_HEADS 16
#define HEAD_DIM  64
#define S_LEN     2048
#define BATCH     2
#define M_TOT     (BATCH * S_LEN)   // 4096

typedef __attribute__((ext_vector_type(8))) short short8;
typedef __attribute__((ext_vector_type(4))) short short4v;
typedef __attribute__((ext_vector_type(4))) float f32x4;

static __device__ __forceinline__ short f2bf(float f) {
    unsigned u = __builtin_bit_cast(unsigned, f);
    unsigned r = (u + 0x7FFFu + ((u >> 16) & 1u)) >> 16;   // RNE
    return (short)r;
}
static __device__ __forceinline__ float bf2f(short s) {
    return __builtin_bit_cast(float, ((unsigned)(unsigned short)s) << 16);
}

typedef __attribute__((address_space(3))) void lds_v;
typedef const __attribute__((address_space(1))) void glb_v;
static __device__ __forceinline__ void gll16(const void* g, void* l) {
    // async global->LDS, 16B/lane, dest = wave-uniform base + lane*16
    __builtin_amdgcn_global_load_lds((glb_v*)g, (lds_v*)l, 16, 0, 0);
}

// ===========================================================================
// FAST PATH kernels
// ===========================================================================

// --- fused converts: blocks [0,2048) convert x; [2048,2304) transpose W -----
__global__ __launch_bounds__(256) void cvt_xw_kernel(
    const float* __restrict__ x, short* __restrict__ xb,
    const float* __restrict__ W, short* __restrict__ wt)
{
    __shared__ short T[64][72];
    const int bx = blockIdx.x;
    if (bx < 2048) {
        int i = (bx * 256 + threadIdx.x) * 8;
        float4 a = *(const float4*)(x + i);
        float4 b = *(const float4*)(x + i + 4);
        short8 o;
        o[0] = f2bf(a.x); o[1] = f2bf(a.y); o[2] = f2bf(a.z); o[3] = f2bf(a.w);
        o[4] = f2bf(b.x); o[5] = f2bf(b.y); o[6] = f2bf(b.z); o[7] = f2bf(b.w);
        *(short8*)(xb + i) = o;
    } else {
        const int t = bx - 2048;
        const int tid = threadIdx.x;
        const int k0 = (t >> 4) * 64, n0 = (t & 15) * 64;
        const int r = tid >> 4, c4 = (tid & 15) * 4;
        #pragma unroll
        for (int i = 0; i < 4; i++) {
            int kr = r + 16 * i;
            float4 v = *(const float4*)(W + (size_t)(k0 + kr) * D_MODEL + n0 + c4);
            short4v s;
            s[0] = f2bf(v.x); s[1] = f2bf(v.y); s[2] = f2bf(v.z); s[3] = f2bf(v.w);
            *(short4v*)&T[kr][c4] = s;
        }
        __syncthreads();
        const int n = tid >> 2, kb = (tid & 3) * 16;
        short tmp[16];
        #pragma unroll
        for (int j = 0; j < 16; j++) tmp[j] = T[kb + j][n];
        *(short8*)(wt + (size_t)(n0 + n) * D_MODEL + k0 + kb)     = *(short8*)&tmp[0];
        *(short8*)(wt + (size_t)(n0 + n) * D_MODEL + k0 + kb + 8) = *(short8*)&tmp[8];
    }
}

// --- bf16 MFMA GEMM + fused QKV epilogue ------------------------------------
// 64x128 C-tile, BK=128 (8 K-iters, half the barrier drains of BK=64).
// XOR-swizzled LDS staging via global_load_lds (source-permuted, 16-slot key).
__global__ __launch_bounds__(256) void gemm_qkv_kernel(
    const short* __restrict__ xb, const short* __restrict__ wt,
    const float* __restrict__ bias, const float* __restrict__ dq,
    const float* __restrict__ dk, const float* __restrict__ dv,
    short* __restrict__ Q, short* __restrict__ K, short* __restrict__ Vt)
{
    __shared__ __attribute__((aligned(16))) short lds[24576]; // As 8192 + Bs 16384

    const int tid  = threadIdx.x;
    const int w    = tid >> 6, l = tid & 63;
    const int quad = l >> 4,  c = l & 15;
    const int n0 = blockIdx.x * 128, m0 = blockIdx.y * 64;
    const int wm = (w & 1) * 32, wn = (w >> 1) * 64;
    short* As = lds;          // [64][128]  swizzled (16-slot XOR)
    short* Bs = lds + 8192;   // [128][128] swizzled

    const int sub  = l >> 4;             // row within 4-row staging chunk
    const int slot = l & 15;

    f32x4 acc[2][4];
    #pragma unroll
    for (int mi = 0; mi < 2; mi++)
        #pragma unroll
        for (int ni = 0; ni < 4; ni++) acc[mi][ni] = (f32x4){0.f, 0.f, 0.f, 0.f};

    for (int k0 = 0; k0 < D_MODEL; k0 += 128) {
        __syncthreads();
        #pragma unroll
        for (int i = 0; i < 4; i++) {
            int rbase = 16 * w + 4 * i;
            int row = rbase + sub;
            int ss = slot ^ (row & 15);
            gll16(xb + (size_t)(m0 + row) * D_MODEL + k0 + ss * 8, As + rbase * 128);
        }
        #pragma unroll
        for (int i = 0; i < 8; i++) {
            int rbase = 32 * w + 4 * i;
            int row = rbase + sub;
            int ss = slot ^ (row & 15);
            gll16(wt + (size_t)(n0 + row) * D_MODEL + k0 + ss * 8, Bs + rbase * 128);
        }
        __syncthreads();
        #pragma unroll
        for (int kh = 0; kh < 4; kh++) {
            const int sx = (kh * 4 + quad) ^ c;
            short8 af[2], bf[4];
            #pragma unroll
            for (int mi = 0; mi < 2; mi++)
                af[mi] = *(const short8*)&As[(wm + 16 * mi + c) * 128 + sx * 8];
            #pragma unroll
            for (int ni = 0; ni < 4; ni++)
                bf[ni] = *(const short8*)&Bs[(wn + 16 * ni + c) * 128 + sx * 8];
            #pragma unroll
            for (int mi = 0; mi < 2; mi++)
                #pragma unroll
                for (int ni = 0; ni < 4; ni++)
                    acc[mi][ni] = __builtin_amdgcn_mfma_f32_16x16x32_bf16(
                        af[mi], bf[ni], acc[mi][ni], 0, 0, 0);
        }
    }

    __syncthreads();
    const int b      = m0 >> 11;
    const int s_base = m0 & 2047;
    const int h      = (n0 + wn) >> 6;

    float biasv[4], dqv[4], dkv[4], dvv[4];
    #pragma unroll
    for (int ni = 0; ni < 4; ni++) {
        int n_g = n0 + wn + 16 * ni + c;
        biasv[ni] = bias[n_g]; dqv[ni] = dq[n_g];
        dkv[ni] = dk[n_g];     dvv[ni] = dv[n_g];
    }

    short* E = lds;   // [128 n][72 m]
    #pragma unroll
    for (int mi = 0; mi < 2; mi++) {
        #pragma unroll
        for (int ni = 0; ni < 4; ni++) {
            short4v vv;
            #pragma unroll
            for (int r = 0; r < 4; r++) {
                float xv = acc[mi][ni][r] + biasv[ni];
                int s = s_base + wm + 16 * mi + 4 * quad + r;
                size_t off = (((size_t)(b * NUM_HEADS + h) * S_LEN + s) << 6) + (16 * ni + c);
                Q[off] = f2bf(xv * dqv[ni]);
                K[off] = f2bf(xv * dkv[ni]);
                vv[r]  = f2bf(xv * dvv[ni]);
            }
            int n_l = wn + 16 * ni + c;
            int m_l = wm + 16 * mi + 4 * quad;
            *(short4v*)&E[n_l * 72 + m_l] = vv;
        }
    }
    __syncthreads();
    {
        const int n_l = tid >> 1, mh = (tid & 1) * 32;
        const int h2 = (n0 + n_l) >> 6;
        const int dh = n_l & 63;
        short* dst = Vt + ((size_t)(b * NUM_HEADS + h2) * HEAD_DIM + dh) * S_LEN + s_base;
        #pragma unroll
        for (int ch = 0; ch < 4; ch++) {
            short8 v = *(const short8*)&E[n_l * 72 + mh + ch * 8];
            *(short8*)(dst + mh + ch * 8) = v;
        }
    }
}

// --- split-K attention (register-dieted): 1024 keys per block, 128 q-rows ---
// S computed in two n-halves (16 live s-regs instead of 32) so combined
// VGPR+AGPR fits 128 -> 4 waves/SIMD -> 4 blocks/CU resident.
// O-partials written as bf16; denom via MFMA(P, ones) in C-layout rows.
__global__ __launch_bounds__(256, 4) void attn_split_kernel(
    const short* __restrict__ Q, const short* __restrict__ K,
    const short* __restrict__ Vt, short* __restrict__ Opart,
    float* __restrict__ dpart)
{
    __shared__ __attribute__((aligned(16))) short lds[8192 + 4 * 32 * 88];

    const int tid  = threadIdx.x;
    const int w    = tid >> 6, l = tid & 63;
    const int quad = l >> 4,  c = l & 15;
    const int cx   = c & 7;
    const int qt    = blockIdx.x >> 1;
    const int split = blockIdx.x & 1;
    const int q0 = qt * 128;
    const int h  = blockIdx.y, b = blockIdx.z;
    const size_t bh = (size_t)(b * NUM_HEADS + h);
    const short* Qh  = Q  + bh * S_LEN * HEAD_DIM;
    const short* Kh  = K  + bh * S_LEN * HEAD_DIM;
    const short* Vth = Vt + bh * HEAD_DIM * S_LEN;

    short* Ks = lds;                         // [64][64] swizzled
    short* Vs = lds + 4096;                  // [64][64] d-major, swizzled
    short* Ps = lds + 8192 + w * (32 * 88);  // per-wave [32][88]

    const int srow  = l >> 3;
    const int sslot = (l & 7) ^ srow;

    short8 qf0[2], qf1[2];
    {
        const short* qp0 = Qh + (size_t)(q0 + 32 * w + c) * 64 + quad * 8;
        const short* qp1 = qp0 + 16 * 64;
        qf0[0] = *(const short8*)(qp0);
        qf0[1] = *(const short8*)(qp0 + 32);
        qf1[0] = *(const short8*)(qp1);
        qf1[1] = *(const short8*)(qp1 + 32);
    }

    short8 ones;
    #pragma unroll
    for (int j = 0; j < 8; j++) ones[j] = (short)0x3F80;  // bf16 1.0

    f32x4 o0[4], o1[4], d0a, d1a;
    #pragma unroll
    for (int i = 0; i < 4; i++) {
        o0[i] = (f32x4){0.f, 0.f, 0.f, 0.f};
        o1[i] = (f32x4){0.f, 0.f, 0.f, 0.f};
    }
    d0a = (f32x4){0.f, 0.f, 0.f, 0.f};
    d1a = (f32x4){0.f, 0.f, 0.f, 0.f};

    const int kt_beg = split * (S_LEN / 128);
    for (int kt = kt_beg; kt < kt_beg + S_LEN / 128; kt++) {
        const int k0 = kt * 64;
        __syncthreads();
        #pragma unroll
        for (int i = 0; i < 2; i++) {
            int rbase = 16 * w + 8 * i;
            int row = rbase + srow;
            gll16(Kh + (size_t)(k0 + row) * 64 + sslot * 8, Ks + rbase * 64);
            gll16(Vth + (size_t)row * S_LEN + k0 + sslot * 8, Vs + rbase * 64);
        }
        __syncthreads();

        // S^T in two n-halves (keys 32*nh .. 32*nh+31) to cap live s-regs
        #pragma unroll
        for (int nh = 0; nh < 2; nh++) {
            f32x4 s0[2], s1[2];
            #pragma unroll
            for (int nn = 0; nn < 2; nn++) {
                s0[nn] = (f32x4){0.f, 0.f, 0.f, 0.f};
                s1[nn] = (f32x4){0.f, 0.f, 0.f, 0.f};
            }
            #pragma unroll
            for (int hh = 0; hh < 2; hh++) {
                const int sx = (hh * 4 + quad) ^ cx;
                #pragma unroll
                for (int nn = 0; nn < 2; nn++) {
                    const int n = 2 * nh + nn;
                    short8 kf = *(const short8*)&Ks[(16 * n + c) * 64 + sx * 8];
                    s0[nn] = __builtin_amdgcn_mfma_f32_16x16x32_bf16(kf, qf0[hh], s0[nn], 0, 0, 0);
                    s1[nn] = __builtin_amdgcn_mfma_f32_16x16x32_bf16(kf, qf1[hh], s1[nn], 0, 0, 0);
                }
            }
            #pragma unroll
            for (int nn = 0; nn < 2; nn++) {
                const int n = 2 * nh + nn;
                float nm[4];
                #pragma unroll
                for (int r = 0; r < 4; r++) {
                    float z = __builtin_amdgcn_fmed3f(s0[nn][r], -15.0f, 15.0f);
                    float e = __builtin_amdgcn_exp2f(
                        __builtin_fmaf(z, 1.4426950408889634f, -1.4426950408889634f));
                    nm[r] = fmaxf(__builtin_fmaf(z, 0.1f, e), 0.0f);
                }
                unsigned p0 = __builtin_amdgcn_perm(
                    __builtin_bit_cast(unsigned, nm[1]) + 0x8000u,
                    __builtin_bit_cast(unsigned, nm[0]) + 0x8000u, 0x07060302u);
                unsigned p1 = __builtin_amdgcn_perm(
                    __builtin_bit_cast(unsigned, nm[3]) + 0x8000u,
                    __builtin_bit_cast(unsigned, nm[2]) + 0x8000u, 0x07060302u);
                uint2 pr; pr.x = p0; pr.y = p1;
                *(uint2*)&Ps[c * 88 + 16 * n + 4 * quad] = pr;
            }
            #pragma unroll
            for (int nn = 0; nn < 2; nn++) {
                const int n = 2 * nh + nn;
                float nm[4];
                #pragma unroll
                for (int r = 0; r < 4; r++) {
                    float z = __builtin_amdgcn_fmed3f(s1[nn][r], -15.0f, 15.0f);
                    float e = __builtin_amdgcn_exp2f(
                        __builtin_fmaf(z, 1.4426950408889634f, -1.4426950408889634f));
                    nm[r] = fmaxf(__builtin_fmaf(z, 0.1f, e), 0.0f);
                }
                unsigned p0 = __builtin_amdgcn_perm(
                    __builtin_bit_cast(unsigned, nm[1]) + 0x8000u,
                    __builtin_bit_cast(unsigned, nm[0]) + 0x8000u, 0x07060302u);
                unsigned p1 = __builtin_amdgcn_perm(
                    __builtin_bit_cast(unsigned, nm[3]) + 0x8000u,
                    __builtin_bit_cast(unsigned, nm[2]) + 0x8000u, 0x07060302u);
                uint2 pr; pr.x = p0; pr.y = p1;
                *(uint2*)&Ps[(16 + c) * 88 + 16 * n + 4 * quad] = pr;
            }
        }
        // no barrier: Ps is same-wave produce/consume (lgkmcnt orders it)

        // PV + denominator row-sum; vf read once, used twice
        #pragma unroll
        for (int kh = 0; kh < 2; kh++) {
            short8 pf0 = *(const short8*)&Ps[c * 88 + 32 * kh + 8 * quad];
            short8 pf1 = *(const short8*)&Ps[(16 + c) * 88 + 32 * kh + 8 * quad];
            const int sx = (kh * 4 + quad) ^ cx;
            #pragma unroll
            for (int n2 = 0; n2 < 4; n2++) {
                short8 vf = *(const short8*)&Vs[(16 * n2 + c) * 64 + sx * 8];
                o0[n2] = __builtin_amdgcn_mfma_f32_16x16x32_bf16(pf0, vf, o0[n2], 0, 0, 0);
                o1[n2] = __builtin_amdgcn_mfma_f32_16x16x32_bf16(pf1, vf, o1[n2], 0, 0, 0);
            }
            d0a = __builtin_amdgcn_mfma_f32_16x16x32_bf16(pf0, ones, d0a, 0, 0, 0);
            d1a = __builtin_amdgcn_mfma_f32_16x16x32_bf16(pf1, ones, d1a, 0, 0, 0);
        }
    }

    // --- write partials: Opart bf16 [split][b][h][qt][128][64], dpart fp32 ---
    short* Op = Opart + ((((size_t)split * BATCH + b) * NUM_HEADS + h) * 16 + qt) * (128 * 64);
    float* dp = dpart + ((((size_t)split * BATCH + b) * NUM_HEADS + h) * 16 + qt) * 128;

    #pragma unroll
    for (int r = 0; r < 4; r++) {
        int row0 = 32 * w + 4 * quad + r;
        #pragma unroll
        for (int n2 = 0; n2 < 4; n2++) {
            Op[row0 * 64 + 16 * n2 + c]        = f2bf(o0[n2][r]);
            Op[(row0 + 16) * 64 + 16 * n2 + c] = f2bf(o1[n2][r]);
        }
        if (c == 0) {
            dp[row0]      = d0a[r];
            dp[row0 + 16] = d1a[r];
        }
    }
}

// --- combine: out = (O0 + O1) / (d0 + d1 + eps)  (bf16 partials) ------------
__global__ __launch_bounds__(256) void combine_kernel(
    const short* __restrict__ Opart, const float* __restrict__ dpart,
    float* __restrict__ out)
{
    const int gid = blockIdx.x * 256 + threadIdx.x;   // [0, 1048576)
    const int row = gid >> 4;                          // [0, 65536)
    const int col = (gid & 15) * 4;
    float d = dpart[row] + dpart[65536 + row] + 1e-9f;
    float inv = 1.0f / d;
    short4v a  = *(const short4v*)(Opart + (size_t)gid * 4);
    short4v b2 = *(const short4v*)(Opart + 4194304 + (size_t)gid * 4);
    const int b = row >> 15;
    const int h = (row >> 11) & 15;
    const int s = row & 2047;
    float4 r;
    r.x = (bf2f(a[0]) + bf2f(b2[0])) * inv;
    r.y = (bf2f(a[1]) + bf2f(b2[1])) * inv;
    r.z = (bf2f(a[2]) + bf2f(b2[2])) * inv;
    r.w = (bf2f(a[3]) + bf2f(b2[3])) * inv;
    *(float4*)(out + ((size_t)(b * S_LEN + s) << 10) + (h << 6) + col) = r;
}

// --- middle tier: full-key attention (divides in-kernel) --------------------
__global__ __launch_bounds__(256) void attn2_kernel(
    const short* __restrict__ Q, const short* __restrict__ K,
    const short* __restrict__ Vt, float* __restrict__ out)
{
    __shared__ __attribute__((aligned(16))) short lds[8192 + 4 * 32 * 88];

    const int tid  = threadIdx.x;
    const int w    = tid >> 6, l = tid & 63;
    const int quad = l >> 4,  c = l & 15;
    const int cx   = c & 7;
    const int q0 = blockIdx.x * 128;
    const int h  = blockIdx.y, b = blockIdx.z;
    const size_t bh = (size_t)(b * NUM_HEADS + h);
    const short* Qh  = Q  + bh * S_LEN * HEAD_DIM;
    const short* Kh  = K  + bh * S_LEN * HEAD_DIM;
    const short* Vth = Vt + bh * HEAD_DIM * S_LEN;

    short* Ks = lds;
    short* Vs = lds + 4096;
    short* Ps = lds + 8192 + w * (32 * 88);

    const int srow  = l >> 3;
    const int sslot = (l & 7) ^ srow;

    short8 qf0[2], qf1[2];
    {
        const short* qp0 = Qh + (size_t)(q0 + 32 * w + c) * 64 + quad * 8;
        const short* qp1 = qp0 + 16 * 64;
        qf0[0] = *(const short8*)(qp0);
        qf0[1] = *(const short8*)(qp0 + 32);
        qf1[0] = *(const short8*)(qp1);
        qf1[1] = *(const short8*)(qp1 + 32);
    }

    f32x4 o0[4], o1[4];
    #pragma unroll
    for (int i = 0; i < 4; i++) {
        o0[i] = (f32x4){0.f, 0.f, 0.f, 0.f};
        o1[i] = (f32x4){0.f, 0.f, 0.f, 0.f};
    }
    float dnm0 = 0.0f, dnm1 = 0.0f;

    for (int kt = 0; kt < S_LEN / 64; kt++) {
        const int k0 = kt * 64;
        __syncthreads();
        #pragma unroll
        for (int i = 0; i < 2; i++) {
            int rbase = 16 * w + 8 * i;
            int row = rbase + srow;
            gll16(Kh + (size_t)(k0 + row) * 64 + sslot * 8, Ks + rbase * 64);
            gll16(Vth + (size_t)row * S_LEN + k0 + sslot * 8, Vs + rbase * 64);
        }
        __syncthreads();

        f32x4 s0[4], s1[4];
        #pragma unroll
        for (int n = 0; n < 4; n++) {
            s0[n] = (f32x4){0.f, 0.f, 0.f, 0.f};
            s1[n] = (f32x4){0.f, 0.f, 0.f, 0.f};
        }
        #pragma unroll
        for (int hh = 0; hh < 2; hh++) {
            const int sx = (hh * 4 + quad) ^ cx;
            #pragma unroll
            for (int n = 0; n < 4; n++) {
                short8 kf = *(const short8*)&Ks[(16 * n + c) * 64 + sx * 8];
                s0[n] = __builtin_amdgcn_mfma_f32_16x16x32_bf16(kf, qf0[hh], s0[n], 0, 0, 0);
                s1[n] = __builtin_amdgcn_mfma_f32_16x16x32_bf16(kf, qf1[hh], s1[n], 0, 0, 0);
            }
        }

        #pragma unroll
        for (int n = 0; n < 4; n++) {
            float nm[4];
            #pragma unroll
            for (int r = 0; r < 4; r++) {
                float z = __builtin_amdgcn_fmed3f(s0[n][r], -15.0f, 15.0f);
                float e = __builtin_amdgcn_exp2f(
                    __builtin_fmaf(z, 1.4426950408889634f, -1.4426950408889634f));
                float num = fmaxf(__builtin_fmaf(z, 0.1f, e), 0.0f);
                dnm0 += num;
                nm[r] = num;
            }
            unsigned p0 = __builtin_amdgcn_perm(
                __builtin_bit_cast(unsigned, nm[1]) + 0x8000u,
                __builtin_bit_cast(unsigned, nm[0]) + 0x8000u, 0x07060302u);
            unsigned p1 = __builtin_amdgcn_perm(
                __builtin_bit_cast(unsigned, nm[3]) + 0x8000u,
                __builtin_bit_cast(unsigned, nm[2]) + 0x8000u, 0x07060302u);
            uint2 pr; pr.x = p0; pr.y = p1;
            *(uint2*)&Ps[c * 88 + 16 * n + 4 * quad] = pr;
        }
        #pragma unroll
        for (int n = 0; n < 4; n++) {
            float nm[4];
            #pragma unroll
            for (int r = 0; r < 4; r++) {
                float z = __builtin_amdgcn_fmed3f(s1[n][r], -15.0f, 15.0f);
                float e = __builtin_amdgcn_exp2f(
                    __builtin_fmaf(z, 1.4426950408889634f, -1.4426950408889634f));
                float num = fmaxf(__builtin_fmaf(z, 0.1f, e), 0.0f);
                dnm1 += num;
                nm[r] = num;
            }
            unsigned p0 = __builtin_amdgcn_perm(
                __builtin_bit_cast(unsigned, nm[1]) + 0x8000u,
                __builtin_bit_cast(unsigned, nm[0]) + 0x8000u, 0x07060302u);
            unsigned p1 = __builtin_amdgcn_perm(
                __builtin_bit_cast(unsigned, nm[3]) + 0x8000u,
                __builtin_bit_cast(unsigned, nm[2]) + 0x8000u, 0x07060302u);
            uint2 pr; pr.x = p0; pr.y = p1;
            *(uint2*)&Ps[(16 + c) * 88 + 16 * n + 4 * quad] = pr;
        }

        #pragma unroll
        for (int kh = 0; kh < 2; kh++) {
            short8 pf0 = *(const short8*)&Ps[c * 88 + 32 * kh + 8 * quad];
            short8 pf1 = *(const short8*)&Ps[(16 + c) * 88 + 32 * kh + 8 * quad];
            const int sx = (kh * 4 + quad) ^ cx;
            #pragma unroll
            for (int n2 = 0; n2 < 4; n2++) {
                short8 vf = *(const short8*)&Vs[(16 * n2 + c) * 64 + sx * 8];
                o0[n2] = __builtin_amdgcn_mfma_f32_16x16x32_bf16(pf0, vf, o0[n2], 0, 0, 0);
                o1[n2] = __builtin_amdgcn_mfma_f32_16x16x32_bf16(pf1, vf, o1[n2], 0, 0, 0);
            }
        }
    }

    dnm0 += __shfl_xor(dnm0, 16, 64);
    dnm0 += __shfl_xor(dnm0, 32, 64);
    dnm1 += __shfl_xor(dnm1, 16, 64);
    dnm1 += __shfl_xor(dnm1, 32, 64);

    #pragma unroll
    for (int r = 0; r < 4; r++) {
        float dr0 = __shfl(dnm0, quad * 4 + r, 64);
        float dr1 = __shfl(dnm1, quad * 4 + r, 64);
        float inv0 = 1.0f / (dr0 + 1e-9f);
        float inv1 = 1.0f / (dr1 + 1e-9f);
        int qrow0 = q0 + 32 * w + 4 * quad + r;
        float* op0 = out + ((size_t)(b * S_LEN + qrow0) << 10) + (h << 6) + c;
        float* op1 = op0 + (16 << 10);
        #pragma unroll
        for (int n2 = 0; n2 < 4; n2++) {
            op0[16 * n2] = o0[n2][r] * inv0;
            op1[16 * n2] = o1[n2][r] * inv1;
        }
    }
}

// ===========================================================================
// FALLBACK PATH (fp32, needs 16 MB workspace)
// ===========================================================================
__global__ __launch_bounds__(256, 4) void gemm_xw_kernel(
    const float* __restrict__ x, const float* __restrict__ W,
    const float* __restrict__ bias, float* __restrict__ xp)
{
    __shared__ float Asf[64][36];
    __shared__ float Bsf[32][68];

    const int tid = threadIdx.x;
    const int tx  = tid & 15;
    const int ty  = tid >> 4;
    const int m0  = blockIdx.y * 64;
    const int n0  = blockIdx.x * 64;

    float acc[4][4];
    #pragma unroll
    for (int i = 0; i < 4; i++)
        #pragma unroll
        for (int j = 0; j < 4; j++) acc[i][j] = 0.0f;

    for (int k0 = 0; k0 < D_MODEL; k0 += 32) {
        #pragma unroll
        for (int i = 0; i < 2; i++) {
            int idx = tid + i * 256;
            int r = idx >> 3, c4 = idx & 7;
            *(float4*)(&Asf[r][c4 * 4]) =
                *(const float4*)(x + (size_t)(m0 + r) * D_MODEL + k0 + c4 * 4);
        }
        #pragma unroll
        for (int i = 0; i < 2; i++) {
            int idx = tid + i * 256;
            int r = idx >> 4, c4 = idx & 15;
            *(float4*)(&Bsf[r][c4 * 4]) =
                *(const float4*)(W + (size_t)(k0 + r) * D_MODEL + n0 + c4 * 4);
        }
        __syncthreads();
        #pragma unroll
        for (int k = 0; k < 32; k += 4) {
            float a[4][4];
            #pragma unroll
            for (int i = 0; i < 4; i++) {
                float4 t = *(const float4*)(&Asf[ty + 16 * i][k]);
                a[i][0] = t.x; a[i][1] = t.y; a[i][2] = t.z; a[i][3] = t.w;
            }
            #pragma unroll
            for (int kk = 0; kk < 4; kk++) {
                float4 bv = *(const float4*)(&Bsf[k + kk][tx * 4]);
                #pragma unroll
                for (int i = 0; i < 4; i++) {
                    acc[i][0] += a[i][kk] * bv.x;
                    acc[i][1] += a[i][kk] * bv.y;
                    acc[i][2] += a[i][kk] * bv.z;
                    acc[i][3] += a[i][kk] * bv.w;
                }
            }
        }
        __syncthreads();
    }
    float4 bv = *(const float4*)(bias + n0 + tx * 4);
    #pragma unroll
    for (int i = 0; i < 4; i++) {
        float4 r;
        r.x = acc[i][0] + bv.x; r.y = acc[i][1] + bv.y;
        r.z = acc[i][2] + bv.z; r.w = acc[i][3] + bv.w;
        *(float4*)(xp + (size_t)(m0 + ty + 16 * i) * D_MODEL + n0 + tx * 4) = r;
    }
}

__global__ __launch_bounds__(256, 4) void attn_fb_kernel(
    const float* __restrict__ xp, const float* __restrict__ dq,
    const float* __restrict__ dk, const float* __restrict__ dv,
    float* __restrict__ out)
{
    __shared__ __attribute__((aligned(16))) short lds[13824];

    const int tid  = threadIdx.x;
    const int wave = tid >> 6;
    const int l    = tid & 63;
    const int quad = l >> 4;
    const int c    = l & 15;
    const int q0   = blockIdx.x * 64;
    const int h    = blockIdx.y;
    const int bb   = blockIdx.z;
    const int col0 = h * HEAD_DIM;
    const float* base = xp + (size_t)bb * S_LEN * D_MODEL;

    short* Ks = lds;
    short* Vt = lds + 64 * 72;
    short* Ps = lds + 2 * 64 * 72 + wave * (16 * 72);

    short8 qf[2];
    {
        const int qrow = q0 + wave * 16 + c;
        const float* qp = base + (size_t)qrow * D_MODEL + col0 + quad * 8;
        const float* sp = dq + col0 + quad * 8;
        #pragma unroll
        for (int hh = 0; hh < 2; hh++) {
            float4 v0 = *(const float4*)(qp + 32 * hh);
            float4 v1 = *(const float4*)(qp + 32 * hh + 4);
            float4 s0 = *(const float4*)(sp + 32 * hh);
            float4 s1 = *(const float4*)(sp + 32 * hh + 4);
            qf[hh][0] = f2bf(v0.x * s0.x); qf[hh][1] = f2bf(v0.y * s0.y);
            qf[hh][2] = f2bf(v0.z * s0.z); qf[hh][3] = f2bf(v0.w * s0.w);
            qf[hh][4] = f2bf(v1.x * s1.x); qf[hh][5] = f2bf(v1.y * s1.y);
            qf[hh][6] = f2bf(v1.z * s1.z); qf[hh][7] = f2bf(v1.w * s1.w);
        }
    }

    const int sc4  = 4 * (tid & 15);
    const int srow = tid >> 4;
    const float4 ksc = *(const float4*)(dk + col0 + sc4);
    const int vd = tid & 63;
    const int vg = tid >> 6;
    const float vsc = dv[col0 + vd];

    f32x4 acc_o[4];
    #pragma unroll
    for (int i = 0; i < 4; i++) acc_o[i] = (f32x4){0.f, 0.f, 0.f, 0.f};
    float dnm = 0.0f;

    for (int kt = 0; kt < S_LEN / 64; kt++) {
        const int k0 = kt * 64;
        __syncthreads();

        #pragma unroll
        for (int i = 0; i < 4; i++) {
            int r = srow + 16 * i;
            float4 v = *(const float4*)(base + (size_t)(k0 + r) * D_MODEL + col0 + sc4);
            short4v s;
            s[0] = f2bf(v.x * ksc.x); s[1] = f2bf(v.y * ksc.y);
            s[2] = f2bf(v.z * ksc.z); s[3] = f2bf(v.w * ksc.w);
            *(short4v*)&Ks[r * 72 + sc4] = s;
        }
        #pragma unroll
        for (int p = 0; p < 4; p++) {
            int kb = 16 * p + 4 * vg;
            const float* vp = base + (size_t)(k0 + kb) * D_MODEL + col0 + vd;
            float a0 = vp[0 * D_MODEL], a1 = vp[1 * D_MODEL];
            float a2 = vp[2 * D_MODEL], a3 = vp[3 * D_MODEL];
            short4v s;
            s[0] = f2bf(a0 * vsc); s[1] = f2bf(a1 * vsc);
            s[2] = f2bf(a2 * vsc); s[3] = f2bf(a3 * vsc);
            *(short4v*)&Vt[vd * 72 + kb] = s;
        }
        __syncthreads();

        f32x4 sacc[4];
        #pragma unroll
        for (int n = 0; n < 4; n++) sacc[n] = (f32x4){0.f, 0.f, 0.f, 0.f};
        #pragma unroll
        for (int n = 0; n < 4; n++)
            #pragma unroll
            for (int hh = 0; hh < 2; hh++) {
                short8 kf = *(const short8*)&Ks[(16 * n + c) * 72 + 32 * hh + 8 * quad];
                sacc[n] = __builtin_amdgcn_mfma_f32_16x16x32_bf16(kf, qf[hh], sacc[n], 0, 0, 0);
            }

        #pragma unroll
        for (int n = 0; n < 4; n++) {
            short4v pp;
            #pragma unroll
            for (int r = 0; r < 4; r++) {
                float z = fminf(fmaxf(sacc[n][r], -15.0f), 15.0f);
                float e = __expf(z - 1.0f);
                float num = fmaxf(fmaf(z, 0.1f, e), 0.0f);
                dnm += num;
                pp[r] = f2bf(num);
            }
            *(short4v*)&Ps[c * 72 + 16 * n + 4 * quad] = pp;
        }

        #pragma unroll
        for (int kh = 0; kh < 2; kh++) {
            short8 pf = *(const short8*)&Ps[c * 72 + 32 * kh + 8 * quad];
            #pragma unroll
            for (int n2 = 0; n2 < 4; n2++) {
                short8 vf = *(const short8*)&Vt[(16 * n2 + c) * 72 + 32 * kh + 8 * quad];
                acc_o[n2] = __builtin_amdgcn_mfma_f32_16x16x32_bf16(pf, vf, acc_o[n2], 0, 0, 0);
            }
        }
    }

    dnm += __shfl_xor(dnm, 16, 64);
    dnm += __shfl_xor(dnm, 32, 64);

    #pragma unroll
    for (int r = 0; r < 4; r++) {
        float dr  = __shfl(dnm, quad * 4 + r, 64);
        float inv = 1.0f / (dr + 1e-9f);
        const int qrow = q0 + wave * 16 + quad * 4 + r;
        float* op = out + (size_t)(bb * S_LEN + qrow) * D_MODEL + col0 + c;
        #pragma unroll
        for (int n2 = 0; n2 < 4; n2++)
            op[16 * n2] = acc_o[n2][r] * inv;
    }
}

// ===========================================================================
extern "C" void kernel_launch(void* const* d_in, const int* in_sizes, int n_in,
                              void* d_out, int out_size, void* d_ws, size_t ws_size,
                              hipStream_t stream) {
    const float* x  = (const float*)d_in[0];
    const float* W  = (const float*)d_in[1];
    const float* bias = (const float*)d_in[2];
    const float* dq = (const float*)d_in[3];
    const float* dk = (const float*)d_in[4];
    const float* dv = (const float*)d_in[5];
    float* out = (float*)d_out;

    const size_t XB_B = (size_t)M_TOT * D_MODEL * 2;        // 8 MB
    const size_t WT_B = (size_t)D_MODEL * D_MODEL * 2;      // 2 MB
    const size_t T_B  = (size_t)BATCH * NUM_HEADS * S_LEN * HEAD_DIM * 2; // 8 MB each
    const size_t OP_B = (size_t)2 * 65536 * 64 * 2;         // 16.78 MB (bf16)
    const size_t DP_B = (size_t)2 * 65536 * 4;              // 512 KB
    const size_t NEED1 = XB_B + WT_B + 3 * T_B;             // ~34 MB
    const size_t NEED2 = NEED1 + OP_B + DP_B;               // ~51.6 MB

    if (ws_size >= NEED1) {
        char* p = (char*)d_ws;
        short* xb = (short*)p;             p += XB_B;
        short* wt = (short*)p;             p += WT_B;
        short* Qt = (short*)p;             p += T_B;
        short* Kt = (short*)p;             p += T_B;
        short* Vt = (short*)p;             p += T_B;

        cvt_xw_kernel<<<2048 + 256, 256, 0, stream>>>(x, xb, W, wt);
        dim3 gg(D_MODEL / 128, M_TOT / 64);                // (8, 64) = 512 blocks
        gemm_qkv_kernel<<<gg, 256, 0, stream>>>(xb, wt, bias, dq, dk, dv, Qt, Kt, Vt);

        if (ws_size >= NEED2) {
            short* Opart = (short*)p;      p += OP_B;
            float* dpart = (float*)p;
            dim3 ga(2 * S_LEN / 128, NUM_HEADS, BATCH);    // (32, 16, 2) = 1024 blocks
            attn_split_kernel<<<ga, 256, 0, stream>>>(Qt, Kt, Vt, Opart, dpart);
            combine_kernel<<<4096, 256, 0, stream>>>(Opart, dpart, out);
        } else {
            dim3 ga(S_LEN / 128, NUM_HEADS, BATCH);        // (16, 16, 2) = 512 blocks
            attn2_kernel<<<ga, 256, 0, stream>>>(Qt, Kt, Vt, out);
        }
    } else {
        float* xp = (float*)d_ws;   // 16 MB
        dim3 g1(D_MODEL / 64, M_TOT / 64);
        gemm_xw_kernel<<<g1, 256, 0, stream>>>(x, W, bias, xp);
        dim3 g2(S_LEN / 64, NUM_HEADS, BATCH);
        attn_fb_kernel<<<g2, 256, 0, stream>>>(xp, dq, dk, dv, out);
    }
}